// Round 1
// baseline (131.753 us; speedup 1.0000x reference)
//
#include <hip/hip_runtime.h>
#include <cmath>

#define DD   10
#define FF   32
#define OUTN 32
#define BVPB 8      // (b,v) pairs per block
#define NT   256

// Kernel 1: summed[b,v,f] = sum_d inputs[b,v,d,f]
__global__ __launch_bounds__(NT) void sum_d_kernel(
    const float* __restrict__ inputs, float* __restrict__ summed, int nBVF) {
    int idx = blockIdx.x * NT + threadIdx.x;
    if (idx >= nBVF) return;
    int f  = idx & (FF - 1);
    int bv = idx >> 5;
    const float* p = inputs + (size_t)bv * (DD * FF) + f;
    float s = 0.f;
#pragma unroll
    for (int d = 0; d < DD; ++d) s += p[d * FF];
    summed[idx] = s;
}

// Kernel 2: gather + mask + dense(F->OUT)+relu + attn dot + softmax(D) + scale
__global__ __launch_bounds__(NT) void gat_kernel(
    const float* __restrict__ summed,
    const float* __restrict__ init,
    const float* __restrict__ mask,
    const float* __restrict__ Wk,
    const float* __restrict__ Wb,
    const float* __restrict__ Ak,
    const int* __restrict__ adj,
    const int* __restrict__ mask_index_p,
    float* __restrict__ out,
    int B, int V) {
    __shared__ float sW[FF * OUTN];          // 4 KB
    __shared__ float sB[OUTN];
    __shared__ float sA[OUTN];
    __shared__ float sGI[BVPB][DD][FF];      // 10 KB  gathered inputs
    __shared__ float sT[BVPB][DD][FF];       // 10 KB  transformed
    __shared__ float sZM[BVPB][DD];          // zero_mask
    __shared__ int   sAdj[BVPB][DD];
    __shared__ float sAttn[BVPB][DD];
    __shared__ float sCoef[BVPB][DD];

    const int t   = threadIdx.x;
    const int bv0 = blockIdx.x * BVPB;
    const int BV  = B * V;
    const int mask_index = *mask_index_p;

    // stage weights
    for (int i = t; i < FF * OUTN; i += NT) sW[i] = Wk[i];
    if (t < OUTN) { sB[t] = Wb[t]; sA[t] = Ak[t]; }
    // stage adj + zero_mask
    if (t < BVPB * DD) {
        int p = t / DD, d = t % DD;
        int bv = bv0 + p;
        float m = 0.f; int a = 0;
        if (bv < BV) { m = mask[bv * DD + d]; a = adj[bv * DD + d]; }
        sZM[p][d] = 1.f - m;
        sAdj[p][d] = a;
    }
    __syncthreads();

    // phase 1: gathered_inputs = zero_mask * (gather(summed, adj) + init)
    for (int idx = t; idx < BVPB * DD * FF; idx += NT) {
        int p   = idx / (DD * FF);
        int rem = idx - p * (DD * FF);
        int d = rem >> 5;
        int f = rem & 31;
        int bv = bv0 + p;
        float gi = 0.f;
        if (bv < BV) {
            int b = bv / V;
            int a = sAdj[p][d];
            float g = 0.f;
            if (a != mask_index) {
                int ac = a < 0 ? 0 : (a >= V ? V - 1 : a);  // JAX clamp semantics
                g = summed[((size_t)b * V + ac) * FF + f];
            }
            gi = sZM[p][d] * (g + init[(size_t)bv * (DD * FF) + rem]);
        }
        sGI[p][d][f] = gi;
    }
    __syncthreads();

    // phase 2: transformed = zero_mask * relu(gi @ W + bias)
    for (int idx = t; idx < BVPB * DD * OUTN; idx += NT) {
        int p   = idx / (DD * OUTN);
        int rem = idx - p * (DD * OUTN);
        int d = rem >> 5;
        int o = rem & 31;
        float acc = sB[o];
#pragma unroll
        for (int f = 0; f < FF; ++f) acc = fmaf(sGI[p][d][f], sW[f * OUTN + o], acc);
        acc = fmaxf(acc, 0.f) * sZM[p][d];
        sT[p][d][o] = acc;
    }
    __syncthreads();

    // phase 3: attn_weight = transformed . a  (+ softmax mask)
    if (t < BVPB * DD) {
        int p = t / DD, d = t % DD;
        float acc = 0.f;
#pragma unroll
        for (int o = 0; o < OUTN; ++o) acc += sT[p][d][o] * sA[o];
        sAttn[p][d] = acc - 1e7f * (1.f - sZM[p][d]);
    }
    __syncthreads();

    // phase 4: softmax over D (10 values) per (b,v)
    if (t < BVPB) {
        float mx = -INFINITY;
#pragma unroll
        for (int d = 0; d < DD; ++d) mx = fmaxf(mx, sAttn[t][d]);
        float s = 0.f;
#pragma unroll
        for (int d = 0; d < DD; ++d) { float e = __expf(sAttn[t][d] - mx); sCoef[t][d] = e; s += e; }
        float inv = 1.f / s;
#pragma unroll
        for (int d = 0; d < DD; ++d) sCoef[t][d] *= inv;
    }
    __syncthreads();

    // phase 5: out = coef * transformed, coalesced
    for (int idx = t; idx < BVPB * DD * OUTN; idx += NT) {
        int p   = idx / (DD * OUTN);
        int rem = idx - p * (DD * OUTN);
        int d = rem >> 5;
        int bv = bv0 + p;
        if (bv < BV)
            out[(size_t)bv0 * (DD * OUTN) + idx] = sCoef[p][d] * sT[p][d][rem & 31];
    }
}

extern "C" void kernel_launch(void* const* d_in, const int* in_sizes, int n_in,
                              void* d_out, int out_size, void* d_ws, size_t ws_size,
                              hipStream_t stream) {
    const float* inputs = (const float*)d_in[0];
    const float* init   = (const float*)d_in[1];
    const float* mask   = (const float*)d_in[2];
    const float* Wk     = (const float*)d_in[3];
    const float* Wb     = (const float*)d_in[4];
    const float* Ak     = (const float*)d_in[5];
    const int*   adj    = (const int*)d_in[6];
    const int*   mip    = (const int*)d_in[7];

    const int B   = 4;
    const int BVD = in_sizes[2];          // B*V*D
    const int V   = BVD / (B * DD);
    const int BV  = B * V;

    float* summed = (float*)d_ws;         // B*V*FF floats = 10.24 MB
    int nBVF = BV * FF;
    hipLaunchKernelGGL(sum_d_kernel, dim3((nBVF + NT - 1) / NT), dim3(NT), 0, stream,
                       inputs, summed, nBVF);
    hipLaunchKernelGGL(gat_kernel, dim3((BV + BVPB - 1) / BVPB), dim3(NT), 0, stream,
                       summed, init, mask, Wk, Wb, Ak, adj, mip, (float*)d_out, B, V);
}